// Round 12
// baseline (606.987 us; speedup 1.0000x reference)
//
#include <hip/hip_runtime.h>
#include <hip/hip_bf16.h>
#include <stdint.h>

// Problem constants (fixed by reference setup)
#define NATOMS 16384          // B*NPB = 512*32
#define ETOT   327680         // NATOMS*K (K=20 neighbors)
#define NLAYER 4

typedef __hip_bfloat16 bf16;
using bf16x8 = __attribute__((ext_vector_type(8))) short;   // MFMA A/B frag (4 VGPRs)
using bf16x4 = __attribute__((ext_vector_type(4))) short;   // 8B packed bf16
using f32x4  = __attribute__((ext_vector_type(4))) float;   // MFMA C/D frag

#define LDSF_STRIDE 260   // f32 words per barrier-bridge row

__device__ __forceinline__ float bf2f(short s) {
  union { float f; unsigned u; } x; x.u = ((unsigned)(unsigned short)s) << 16; return x.f;
}
__device__ __forceinline__ short f2bf(float f) {
  bf16 b = __float2bfloat16(f);
  return *(short*)&b;
}

__device__ __forceinline__ void async16(const void* g, void* l) {
  __builtin_amdgcn_global_load_lds(
      (const __attribute__((address_space(1))) unsigned int*)g,
      (__attribute__((address_space(3))) unsigned int*)l, 16, 0, 0);
}

// ---------------------------------------------------------------------------
// gemm_k (EPI=0 only now): C[64x256] per block; used once for the initial
// Prc = h0 @ Wrc (+be1 fold on cols 0..255, i.e. blockIdx.y==0).
// ---------------------------------------------------------------------------
template<int KTOT, int EPI, int MT>
__global__ void __launch_bounds__(256, 2)
gemm_k(const bf16* A, const bf16* A2, const bf16* B,
       bf16* Obf, int ldOut, const float* bias,
       float* Hf, bf16* Hbf)
{
  __shared__ __align__(16) char smem[49152];
  const int tid  = threadIdx.x;
  const int w    = tid >> 6;
  const int lane = tid & 63;
  const int q    = lane >> 4;
  const int t16  = lane & 15;
  const size_t row0 = (size_t)blockIdx.x * MT;
  const int ncol0 = blockIdx.y * 256;
  constexpr int MI = MT / 16;
  constexpr int AI = MT / 32;

  f32x4 acc[MI][4] = {};
  constexpr int NCHUNK = KTOT / 64;
  for (int kc = 0; kc < NCHUNK; ++kc) {
    const int k0 = kc * 64;
    __syncthreads();
    #pragma unroll
    for (int ii = 0; ii < AI; ++ii) {
      int i = w * AI + ii;
      int f = i * 64 + lane;
      int m = f >> 3, s = f & 7;
      int ko = s ^ (m & 7);
      async16(A + (row0 + (size_t)m) * KTOT + (size_t)(k0 + ko * 8), smem + i * 1024);
    }
    #pragma unroll
    for (int ii = 0; ii < 8; ++ii) {
      int i = w * 8 + ii;
      int f = i * 64 + lane;
      int n = f >> 3, s = f & 7;
      int ko = s ^ (n & 7);
      async16(B + (size_t)(ncol0 + n) * KTOT + (size_t)(k0 + ko * 8),
              smem + 16384 + i * 1024);
    }
    __syncthreads();
    #pragma unroll
    for (int ks = 0; ks < 2; ++ks) {
      bf16x8 av[MI]; bf16x8 bv[4];
      const int ko = q + 4 * ks;
      #pragma unroll
      for (int mi = 0; mi < MI; ++mi) {
        int m = 16 * mi + t16;
        int f = m * 8 + (ko ^ (m & 7));
        av[mi] = *(const bf16x8*)(smem + f * 16);
      }
      #pragma unroll
      for (int ni = 0; ni < 4; ++ni) {
        int n = 64 * w + 16 * ni + t16;
        int f = n * 8 + (ko ^ (n & 7));
        bv[ni] = *(const bf16x8*)(smem + 16384 + f * 16);
      }
      #pragma unroll
      for (int mi = 0; mi < MI; ++mi)
        #pragma unroll
        for (int ni = 0; ni < 4; ++ni)
          acc[mi][ni] = __builtin_amdgcn_mfma_f32_16x16x32_bf16(
              av[mi], bv[ni], acc[mi][ni], 0, 0, 0);
    }
  }

  float* lds_f = (float*)smem;
  #pragma unroll
  for (int mi = 0; mi < MI; ++mi) {
    __syncthreads();
    #pragma unroll
    for (int ni = 0; ni < 4; ++ni)
      #pragma unroll
      for (int r = 0; r < 4; ++r)
        lds_f[(4 * q + r) * LDSF_STRIDE + 64 * w + 16 * ni + t16] = acc[mi][ni][r];
    __syncthreads();
    #pragma unroll
    for (int j = 0; j < 2; ++j) {
      int task = tid + 256 * j;
      int rr = task >> 5, cg = task & 31;
      int c0 = cg * 8;
      size_t rg = row0 + 16 * mi + rr;
      f32x4 v0 = *(const f32x4*)(lds_f + rr * LDSF_STRIDE + c0);
      f32x4 v1 = *(const f32x4*)(lds_f + rr * LDSF_STRIDE + c0 + 4);
      float v[8] = {v0[0], v0[1], v0[2], v0[3], v1[0], v1[1], v1[2], v1[3]};
      bf16x8 o;
      #pragma unroll
      for (int k = 0; k < 8; ++k) {
        float vv = v[k];
        if (bias != nullptr && ncol0 == 0) vv += bias[c0 + k];
        o[k] = f2bf(vv);
      }
      *(bf16x8*)(Obf + rg * ldOut + (ncol0 + c0)) = o;
    }
  }
}

// ---------------------------------------------------------------------------
// Fused edge pipeline v5 (r11-verified) minus be1 (now folded into Prc).
// ---------------------------------------------------------------------------
#define WINC 40960
#define WINR 57856
#define SCOL 59968
#define SRAD 60288
#define WPITCH 528

__global__ void __launch_bounds__(256, 2)
edge_fused(const bf16* Wgp_l, const bf16* W2p_l, const float* off,
           const float* pos, const int* eidx, const bf16* Prc,
           const float* wrad, const float* be2, bf16* Agg)
{
  __shared__ __align__(16) char smem[60608];
  int*   s_col = (int*)  (smem + SCOL);
  float* s_rad = (float*)(smem + SRAD);

  const int tid  = threadIdx.x;
  const int w    = tid >> 6;
  const int lane = tid & 63;
  const int q    = lane >> 4;
  const int t16  = lane & 15;
  const int blk  = blockIdx.x;
  const int node0  = (blk >> 3) * 32;
  const int rnode0 = blk * 4;
  const int ebase  = blk * 80;

  bf16x8 wgf[4][2];
  #pragma unroll
  for (int fi = 0; fi < 4; ++fi)
    #pragma unroll
    for (int ks = 0; ks < 2; ++ks)
      wgf[fi][ks] = *(const bf16x8*)(Wgp_l + (size_t)(((fi * 2 + ks) * 4 + w) * 512)
                                     + lane * 8);

  {
    int row = tid >> 3, seg = tid & 7;
    const bf16* src = Prc + (size_t)(node0 + row) * 512 + 256 + seg * 32;
    char* dst = smem + WINC + row * WPITCH + seg * 64;
    #pragma unroll
    for (int j = 0; j < 4; ++j)
      *(bf16x8*)(dst + j * 16) = *(const bf16x8*)(src + j * 8);
  }
  if (tid < 128) {
    int row = tid >> 5, seg = tid & 31;
    *(bf16x8*)(smem + WINR + row * WPITCH + seg * 16) =
        *(const bf16x8*)(Prc + (size_t)(rnode0 + row) * 512 + seg * 8);
  }

  if (tid < 80) {
    int e = ebase + tid;
    int rg = rnode0 + tid / 20;            // row node = e/20 (setup identity)
    int cg = eidx[ETOT + e];
    float dx = pos[cg * 3 + 0] - pos[rg * 3 + 0];
    float dy = pos[cg * 3 + 1] - pos[rg * 3 + 1];
    float dz = pos[cg * 3 + 2] - pos[rg * 3 + 2];
    float d2 = dx * dx + dy * dy + dz * dz;
    s_col[tid] = cg & 31;
    s_rad[tid] = 0.01f * d2;
    float d = sqrtf(d2);
    const float GC = -0.5f / ((5.0f / 63.0f) * (5.0f / 63.0f));
    #pragma unroll
    for (int oct = 0; oct < 8; ++oct) {
      bf16x8 v;
      #pragma unroll
      for (int j = 0; j < 8; ++j) {
        float t = d - off[oct * 8 + j];
        v[j] = f2bf(__expf(GC * t * t));
      }
      int f = tid * 8 + (oct ^ (tid & 7));
      *(bf16x8*)(smem + f * 16) = v;
    }
  }
  __syncthreads();                         // (#1)

  f32x4 acc1[4][5] = {};
  #pragma unroll
  for (int ks = 0; ks < 2; ++ks) {
    const int ko = q + 4 * ks;
    bf16x8 gv[5];
    #pragma unroll
    for (int ci = 0; ci < 5; ++ci) {
      int e = 16 * ci + t16;
      int f = e * 8 + (ko ^ (e & 7));
      gv[ci] = *(const bf16x8*)(smem + f * 16);
    }
    #pragma unroll
    for (int fi = 0; fi < 4; ++fi)
      #pragma unroll
      for (int ci = 0; ci < 5; ++ci)
        acc1[fi][ci] = __builtin_amdgcn_mfma_f32_16x16x32_bf16(
            wgf[fi][ks], gv[ci], acc1[fi][ci], 0, 0, 0);
  }
  __syncthreads();                         // (#2)

  {
    f32x4 tw[4];
    #pragma unroll
    for (int fi = 0; fi < 4; ++fi)
      tw[fi] = *(const f32x4*)(wrad + 64 * w + 16 * fi + 4 * q);
    #pragma unroll
    for (int ci = 0; ci < 5; ++ci) {
      int e = 16 * ci + t16;
      int rl = e / 20;
      int cl = s_col[e];
      float rad = s_rad[e];
      #pragma unroll
      for (int fi = 0; fi < 4; ++fi) {
        int fb = 64 * w + 16 * fi + 4 * q;
        bf16x4 pr = *(const bf16x4*)(smem + WINR + rl * WPITCH + fb * 2);
        bf16x4 pc = *(const bf16x4*)(smem + WINC + cl * WPITCH + fb * 2);
        bf16x4 o;
        #pragma unroll
        for (int r = 0; r < 4; ++r) {
          float val = acc1[fi][ci][r] + rad * tw[fi][r]
                    + bf2f(pr[r]) + bf2f(pc[r]);
          o[r] = f2bf(fmaxf(val, 0.f));
        }
        int u = (16 * w + 4 * fi + q) ^ (e & 14);
        *(bf16x4*)(smem + e * 512 + u * 8) = o;
      }
    }
  }
  __syncthreads();                         // (#3)

  f32x4 acc2[5][4] = {};
  #pragma unroll
  for (int kc = 0; kc < 4; ++kc) {
    bf16x8 bv[4][2];
    #pragma unroll
    for (int ni = 0; ni < 4; ++ni)
      #pragma unroll
      for (int ks = 0; ks < 2; ++ks) {
        int frag = kc * 8 + ks * 4 + ni;
        bv[ni][ks] = *(const bf16x8*)(W2p_l + (size_t)((frag * 4 + w) * 512)
                                      + lane * 8);
      }
    #pragma unroll
    for (int ks = 0; ks < 2; ++ks) {
      const int ko = q + 4 * ks;
      bf16x8 av[5];
      #pragma unroll
      for (int mi = 0; mi < 5; ++mi) {
        int e = 16 * mi + t16;
        int ub = (2 * (8 * kc + ko)) ^ (t16 & 14);
        av[mi] = *(const bf16x8*)(smem + e * 512 + ub * 8);
      }
      #pragma unroll
      for (int mi = 0; mi < 5; ++mi)
        #pragma unroll
        for (int ni = 0; ni < 4; ++ni)
          acc2[mi][ni] = __builtin_amdgcn_mfma_f32_16x16x32_bf16(
              av[mi], bv[ni][ks], acc2[mi][ni], 0, 0, 0);
    }
  }

  #pragma unroll
  for (int ni = 0; ni < 4; ++ni) {
    float b = be2[64 * w + 16 * ni + t16];
    float pp[5];
    #pragma unroll
    for (int mi = 0; mi < 5; ++mi) {
      float s = 0.f;
      #pragma unroll
      for (int r = 0; r < 4; ++r) s += fmaxf(acc2[mi][ni][r] + b, 0.f);
      pp[mi] = s;
    }
    #pragma unroll
    for (int nn = 0; nn < 4; ++nn) {
      float s = 0.f;
      #pragma unroll
      for (int mi = 0; mi < 5; ++mi) {
        int g = 4 * mi + q;
        if (g >= 5 * nn && g <= 5 * nn + 4) s += pp[mi];
      }
      s += __shfl_xor(s, 16, 64);
      s += __shfl_xor(s, 32, 64);
      if (q == nn)
        Agg[(size_t)(rnode0 + nn) * 256 + 64 * w + 16 * ni + t16] =
            __float2bfloat16(s);
    }
  }
}

// ---------------------------------------------------------------------------
// node_fused: one kernel per layer for the whole node side.
//   t  = relu([h|agg] @ Wn1 + bn1)        (GEMM1, staged; t -> LDS T-tile)
//   h' = 2h + (t @ Wn2 + bn2)             (GEMM2, packed B; h' -> Hf/Hbf/T)
//   Prc_next = h' @ Wrc (+be1 on cols<256) (GEMM3, packed B; skip last layer)
// 64 rows per block, 256 blocks. T-tile layout: row r, 16B octet slot
// s = (koct & 24) | ((koct & 7) ^ (r & 7)); read side koct = (q+4ks)+8kc,
// r & 7 == t16 & 7.
// ---------------------------------------------------------------------------
template<bool DO_PRC>
__global__ void __launch_bounds__(256)
node_fused(const bf16* Hbf_in, const bf16* Agg, const bf16* Wn1T_l,
           const bf16* Wn2p_l, const bf16* Wrcp_n,
           const float* bn1, const float* bn2, const float* be1_n,
           float* Hf, bf16* Hbf, bf16* Prc)
{
  __shared__ __align__(16) char smem[73728];  // staging A 8K | B 32K @8192 | T 32K @40960
  __shared__ float s_bn1[256];
  __shared__ float s_bn2[256];
  char* T = smem + 40960;

  const int tid  = threadIdx.x;
  const int w    = tid >> 6;
  const int lane = tid & 63;
  const int q    = lane >> 4;
  const int t16  = lane & 15;
  const size_t row0 = (size_t)blockIdx.x * 64;

  s_bn1[tid] = bn1[tid];
  s_bn2[tid] = bn2[tid];

  // ---- GEMM1: [h|agg](64x512) @ Wn1 -> acc ----
  f32x4 acc[4][4] = {};
  for (int kc = 0; kc < 8; ++kc) {
    const bf16* Asrc = (kc < 4) ? Hbf_in : Agg;
    const int k0e = (kc & 3) * 64;
    __syncthreads();
    #pragma unroll
    for (int ii = 0; ii < 2; ++ii) {
      int i = w * 2 + ii;
      int f = i * 64 + lane;
      int m = f >> 3, s = f & 7;
      int ko = s ^ (m & 7);
      async16(Asrc + (row0 + (size_t)m) * 256 + (size_t)(k0e + ko * 8),
              smem + i * 1024);
    }
    #pragma unroll
    for (int ii = 0; ii < 8; ++ii) {
      int i = w * 8 + ii;
      int f = i * 64 + lane;
      int n = f >> 3, s = f & 7;
      int ko = s ^ (n & 7);
      async16(Wn1T_l + (size_t)n * 512 + (size_t)(kc * 64 + ko * 8),
              smem + 8192 + i * 1024);
    }
    __syncthreads();
    #pragma unroll
    for (int ks = 0; ks < 2; ++ks) {
      bf16x8 av[4]; bf16x8 bv[4];
      const int ko = q + 4 * ks;
      #pragma unroll
      for (int mi = 0; mi < 4; ++mi) {
        int m = 16 * mi + t16;
        int f = m * 8 + (ko ^ (m & 7));
        av[mi] = *(const bf16x8*)(smem + f * 16);
      }
      #pragma unroll
      for (int ni = 0; ni < 4; ++ni) {
        int n = 64 * w + 16 * ni + t16;
        int f = n * 8 + (ko ^ (n & 7));
        bv[ni] = *(const bf16x8*)(smem + 8192 + f * 16);
      }
      #pragma unroll
      for (int mi = 0; mi < 4; ++mi)
        #pragma unroll
        for (int ni = 0; ni < 4; ++ni)
          acc[mi][ni] = __builtin_amdgcn_mfma_f32_16x16x32_bf16(
              av[mi], bv[ni], acc[mi][ni], 0, 0, 0);
    }
  }

  float* lds_f = (float*)smem;
  // ---- bridge1: t = relu(acc + bn1) -> T-tile ----
  #pragma unroll
  for (int mi = 0; mi < 4; ++mi) {
    __syncthreads();
    #pragma unroll
    for (int ni = 0; ni < 4; ++ni)
      #pragma unroll
      for (int r = 0; r < 4; ++r)
        lds_f[(4 * q + r) * LDSF_STRIDE + 64 * w + 16 * ni + t16] = acc[mi][ni][r];
    __syncthreads();
    #pragma unroll
    for (int j = 0; j < 2; ++j) {
      int task = tid + 256 * j;
      int rr = task >> 5, cg = task & 31;
      int c0 = cg * 8;
      int rl = 16 * mi + rr;
      f32x4 v0 = *(const f32x4*)(lds_f + rr * LDSF_STRIDE + c0);
      f32x4 v1 = *(const f32x4*)(lds_f + rr * LDSF_STRIDE + c0 + 4);
      float v[8] = {v0[0], v0[1], v0[2], v0[3], v1[0], v1[1], v1[2], v1[3]};
      bf16x8 o;
      #pragma unroll
      for (int k = 0; k < 8; ++k) o[k] = f2bf(fmaxf(v[k] + s_bn1[c0 + k], 0.f));
      int s = (cg & 24) | ((cg & 7) ^ (rl & 7));
      *(bf16x8*)(T + rl * 512 + s * 16) = o;
    }
  }
  __syncthreads();

  // ---- GEMM2: t @ Wn2 (K=256), A from T, B packed-global ----
  f32x4 acc2[4][4] = {};
  #pragma unroll
  for (int kc = 0; kc < 4; ++kc) {
    bf16x8 bv[4][2];
    #pragma unroll
    for (int ni = 0; ni < 4; ++ni)
      #pragma unroll
      for (int ks = 0; ks < 2; ++ks) {
        int frag = kc * 8 + ks * 4 + ni;
        bv[ni][ks] = *(const bf16x8*)(Wn2p_l + (size_t)((frag * 4 + w) * 512)
                                      + lane * 8);
      }
    #pragma unroll
    for (int ks = 0; ks < 2; ++ks) {
      const int ko = q + 4 * ks;
      bf16x8 av[4];
      #pragma unroll
      for (int mi = 0; mi < 4; ++mi) {
        int row = 16 * mi + t16;
        int s = 8 * kc + (ko ^ (t16 & 7));
        av[mi] = *(const bf16x8*)(T + row * 512 + s * 16);
      }
      #pragma unroll
      for (int mi = 0; mi < 4; ++mi)
        #pragma unroll
        for (int ni = 0; ni < 4; ++ni)
          acc2[mi][ni] = __builtin_amdgcn_mfma_f32_16x16x32_bf16(
              av[mi], bv[ni][ks], acc2[mi][ni], 0, 0, 0);
    }
  }

  // ---- bridge2: h' = 2h + acc2 + bn2 -> Hf, Hbf, T ----
  #pragma unroll
  for (int mi = 0; mi < 4; ++mi) {
    __syncthreads();
    #pragma unroll
    for (int ni = 0; ni < 4; ++ni)
      #pragma unroll
      for (int r = 0; r < 4; ++r)
        lds_f[(4 * q + r) * LDSF_STRIDE + 64 * w + 16 * ni + t16] = acc2[mi][ni][r];
    __syncthreads();
    #pragma unroll
    for (int j = 0; j < 2; ++j) {
      int task = tid + 256 * j;
      int rr = task >> 5, cg = task & 31;
      int c0 = cg * 8;
      int rl = 16 * mi + rr;
      size_t rg = row0 + rl;
      f32x4 v0 = *(const f32x4*)(lds_f + rr * LDSF_STRIDE + c0);
      f32x4 v1 = *(const f32x4*)(lds_f + rr * LDSF_STRIDE + c0 + 4);
      float v[8] = {v0[0], v0[1], v0[2], v0[3], v1[0], v1[1], v1[2], v1[3]};
      f32x4 h0 = *(const f32x4*)(Hf + rg * 256 + c0);
      f32x4 h1 = *(const f32x4*)(Hf + rg * 256 + c0 + 4);
      float hh[8] = {h0[0], h0[1], h0[2], h0[3], h1[0], h1[1], h1[2], h1[3]};
      bf16x8 o; f32x4 n0, n1;
      #pragma unroll
      for (int k = 0; k < 8; ++k) {
        float hn = 2.f * hh[k] + v[k] + s_bn2[c0 + k];
        o[k] = f2bf(hn);
        if (k < 4) n0[k] = hn; else n1[k - 4] = hn;
      }
      *(f32x4*)(Hf + rg * 256 + c0)     = n0;
      *(f32x4*)(Hf + rg * 256 + c0 + 4) = n1;
      *(bf16x8*)(Hbf + rg * 256 + c0) = o;
      int s = (cg & 24) | ((cg & 7) ^ (rl & 7));
      *(bf16x8*)(T + rl * 512 + s * 16) = o;
    }
  }

  // ---- GEMM3 + epilogue: Prc_next = h' @ Wrc (+be1 on nh==0) ----
  if constexpr (DO_PRC) {
    __syncthreads();
    #pragma unroll
    for (int nh = 0; nh < 2; ++nh) {
      f32x4 acc3[4][4] = {};
      #pragma unroll
      for (int kc = 0; kc < 4; ++kc) {
        bf16x8 bv[4][2];
        #pragma unroll
        for (int ni = 0; ni < 4; ++ni)
          #pragma unroll
          for (int ks = 0; ks < 2; ++ks) {
            int frag = kc * 8 + ks * 4 + ni;
            bv[ni][ks] = *(const bf16x8*)(Wrcp_n + (size_t)nh * 65536 +
                                          (size_t)((frag * 4 + w) * 512) + lane * 8);
          }
        #pragma unroll
        for (int ks = 0; ks < 2; ++ks) {
          const int ko = q + 4 * ks;
          bf16x8 av[4];
          #pragma unroll
          for (int mi = 0; mi < 4; ++mi) {
            int row = 16 * mi + t16;
            int s = 8 * kc + (ko ^ (t16 & 7));
            av[mi] = *(const bf16x8*)(T + row * 512 + s * 16);
          }
          #pragma unroll
          for (int mi = 0; mi < 4; ++mi)
            #pragma unroll
            for (int ni = 0; ni < 4; ++ni)
              acc3[mi][ni] = __builtin_amdgcn_mfma_f32_16x16x32_bf16(
                  av[mi], bv[ni][ks], acc3[mi][ni], 0, 0, 0);
        }
      }
      #pragma unroll
      for (int mi = 0; mi < 4; ++mi) {
        __syncthreads();
        #pragma unroll
        for (int ni = 0; ni < 4; ++ni)
          #pragma unroll
          for (int r = 0; r < 4; ++r)
            lds_f[(4 * q + r) * LDSF_STRIDE + 64 * w + 16 * ni + t16] = acc3[mi][ni][r];
        __syncthreads();
        #pragma unroll
        for (int j = 0; j < 2; ++j) {
          int task = tid + 256 * j;
          int rr = task >> 5, cg = task & 31;
          int c0 = cg * 8;
          size_t rg = row0 + 16 * mi + rr;
          f32x4 v0 = *(const f32x4*)(lds_f + rr * LDSF_STRIDE + c0);
          f32x4 v1 = *(const f32x4*)(lds_f + rr * LDSF_STRIDE + c0 + 4);
          float v[8] = {v0[0], v0[1], v0[2], v0[3], v1[0], v1[1], v1[2], v1[3]};
          bf16x8 o;
          #pragma unroll
          for (int k = 0; k < 8; ++k) {
            float vv = v[k];
            if (nh == 0) vv += be1_n[c0 + k];
            o[k] = f2bf(vv);
          }
          *(bf16x8*)(Prc + rg * 512 + nh * 256 + c0) = o;
        }
      }
    }
  }
}

// ---------------------------------------------------------------------------
// Prep kernels
// ---------------------------------------------------------------------------
__global__ void wrct_kernel(const float* We1, bf16* WrcT) {
  int idx = blockIdx.x * 256 + threadIdx.x;         // 512*256 (layer 0 only)
  int k = idx & 255, np = (idx >> 8) & 511;
  float v = (np < 256)
      ? We1[((size_t)k) * 256 + np]
      : We1[((size_t)256 + k) * 256 + (np - 256)];
  WrcT[idx] = __float2bfloat16(v);
}
// packed Wg fragments: [l][fi*2+ks][w][lane][j]
__global__ void wgp_kernel(const float* We1, bf16* Wgp) {
  int idx = blockIdx.x * 256 + threadIdx.x;         // L*16384
  int i = idx & 16383, l = idx >> 14;
  int j = i & 7, lane = (i >> 3) & 63, w = (i >> 9) & 3, fr = i >> 11;
  int fi = fr >> 1, ks = fr & 1;
  int t16 = lane & 15, q = lane >> 4;
  int g = (q + 4 * ks) * 8 + j;
  int feat = 64 * w + 16 * fi + t16;
  Wgp[idx] = __float2bfloat16(We1[((size_t)l * 577 + 513 + g) * 256 + feat]);
}
// generic 256x256 weight -> packed fragments [l][kc*8+ks*4+ni][w][lane][j]
__global__ void w2p_kernel(const float* W, bf16* Wp) {
  int idx = blockIdx.x * 256 + threadIdx.x;         // L*65536
  int i = idx & 65535, l = idx >> 16;
  int j = i & 7, lane = (i >> 3) & 63, w = (i >> 9) & 3, fr = i >> 11;
  int ni = fr & 3, ks = (fr >> 2) & 1, kc = fr >> 3;
  int t16 = lane & 15, q = lane >> 4;
  int k = kc * 64 + (q + 4 * ks) * 8 + j;
  int n = 64 * w + 16 * ni + t16;
  Wp[idx] = __float2bfloat16(W[((size_t)l * 256 + k) * 256 + n]);
}
// Wrc packed fragments: [l][nh][kc*8+ks*4+ni][w][lane][j], src We1 rows nh*256+k
__global__ void wrcp_kernel(const float* We1, bf16* Wrcp) {
  int idx = blockIdx.x * 256 + threadIdx.x;         // L*2*65536
  int i = idx & 65535, nh = (idx >> 16) & 1, l = idx >> 17;
  int j = i & 7, lane = (i >> 3) & 63, w = (i >> 9) & 3, fr = i >> 11;
  int ni = fr & 3, ks = (fr >> 2) & 1, kc = fr >> 3;
  int t16 = lane & 15, q = lane >> 4;
  int k = kc * 64 + (q + 4 * ks) * 8 + j;
  int n = 64 * w + 16 * ni + t16;
  Wrcp[idx] = __float2bfloat16(We1[((size_t)l * 577 + nh * 256 + k) * 256 + n]);
}
__global__ void wrad_kernel(const float* We1, float* wrad) {
  int idx = blockIdx.x * 256 + threadIdx.x;         // L*256
  int n = idx & 255, l = idx >> 8;
  wrad[idx] = We1[((size_t)l * 577 + 512) * 256 + n];
}
__global__ void trans_kernel(const float* src, bf16* dst, int R, int C) {
  int idx = blockIdx.x * 256 + threadIdx.x;         // L*C*R, dst [l][n][k]
  int k = idx % R, rest = idx / R;
  int n = rest % C, l = rest / C;
  dst[idx] = __float2bfloat16(src[((size_t)l * R + k) * C + n]);
}

__global__ void h0_kernel(const int* types, const float* emb, float* h, bf16* hbf) {
  int i = blockIdx.x, c = threadIdx.x;
  float v = emb[(size_t)(types[i] - 1) * 256 + c];
  h[(size_t)i * 256 + c] = v;
  hbf[(size_t)i * 256 + c] = __float2bfloat16(v);
}

__global__ void pool_kernel(const float* h, float* out) {
  int b = blockIdx.x, c = threadIdx.x;
  float s = 0.f;
  #pragma unroll
  for (int j = 0; j < 32; ++j) s += h[((size_t)b * 32 + j) * 256 + c];
  out[(size_t)b * 256 + c] = s * (1.0f / 32.0f);
}

// ---------------------------------------------------------------------------
extern "C" void kernel_launch(void* const* d_in, const int* in_sizes, int n_in,
                              void* d_out, int out_size, void* d_ws, size_t ws_size,
                              hipStream_t stream) {
  const float* pos   = (const float*)d_in[0];
  const int*   atype = (const int*)  d_in[1];
  const int*   eidx  = (const int*)  d_in[2];
  const float* emb   = (const float*)d_in[4];
  const float* off   = (const float*)d_in[5];
  const float* We1   = (const float*)d_in[6];
  const float* be1   = (const float*)d_in[7];
  const float* We2   = (const float*)d_in[8];
  const float* be2   = (const float*)d_in[9];
  const float* Wn1   = (const float*)d_in[10];
  const float* bn1   = (const float*)d_in[11];
  const float* Wn2   = (const float*)d_in[12];
  const float* bn2   = (const float*)d_in[13];
  float* out = (float*)d_out;

  size_t o = 0;
  auto carve = [&](size_t bytes) {
    void* p = (char*)d_ws + o;
    o += (bytes + 255) & ~(size_t)255;
    return p;
  };
  float* h     = (float*)carve((size_t)NATOMS * 256 * 4);   // 16 MB
  bf16*  hbf   = (bf16*) carve((size_t)NATOMS * 256 * 2);   //  8 MB
  bf16*  Prc   = (bf16*) carve((size_t)NATOMS * 512 * 2);   // 16 MB
  bf16*  aggbf = (bf16*) carve((size_t)NATOMS * 256 * 2);   //  8 MB
  bf16*  WrcT  = (bf16*) carve((size_t)512 * 256 * 2);      // layer-0 only
  bf16*  Wgp   = (bf16*) carve((size_t)NLAYER * 16384 * 2);
  bf16*  W2p   = (bf16*) carve((size_t)NLAYER * 65536 * 2);
  bf16*  Wn1T  = (bf16*) carve((size_t)NLAYER * 256 * 512 * 2);
  bf16*  Wn2p  = (bf16*) carve((size_t)NLAYER * 65536 * 2);
  bf16*  Wrcp  = (bf16*) carve((size_t)NLAYER * 2 * 65536 * 2);
  float* wradp = (float*)carve((size_t)NLAYER * 256 * 4);

  // ---- prep ----
  wrct_kernel<<< 512, 256, 0, stream>>>(We1, WrcT);
  wgp_kernel <<< 256, 256, 0, stream>>>(We1, Wgp);
  w2p_kernel <<<1024, 256, 0, stream>>>(We2, W2p);
  w2p_kernel <<<1024, 256, 0, stream>>>(Wn2, Wn2p);
  wrcp_kernel<<<2048, 256, 0, stream>>>(We1, Wrcp);
  wrad_kernel<<<   4, 256, 0, stream>>>(We1, wradp);
  trans_kernel<<<2048, 256, 0, stream>>>(Wn1, Wn1T, 512, 256);
  h0_kernel  <<<NATOMS, 256, 0, stream>>>(atype, emb, h, hbf);

  // initial Prc for layer 0 (be1 folded into cols 0..255)
  gemm_k<256, 0, 64><<<dim3(256, 2), 256, 0, stream>>>(
      hbf, nullptr, WrcT, Prc, 512, be1, nullptr, nullptr);

  for (int l = 0; l < NLAYER; ++l) {
    edge_fused<<<ETOT / 80, 256, 0, stream>>>(
        Wgp + (size_t)l * 16384, W2p + (size_t)l * 65536, off, pos,
        eidx, Prc, wradp + l * 256, be2 + l * 256, aggbf);
    if (l < NLAYER - 1) {
      node_fused<true><<<256, 256, 0, stream>>>(
          hbf, aggbf, Wn1T + (size_t)l * 131072, Wn2p + (size_t)l * 65536,
          Wrcp + (size_t)(l + 1) * 131072, bn1 + l * 256, bn2 + l * 256,
          be1 + (l + 1) * 256, h, hbf, Prc);
    } else {
      node_fused<false><<<256, 256, 0, stream>>>(
          hbf, aggbf, Wn1T + (size_t)l * 131072, Wn2p + (size_t)l * 65536,
          nullptr, bn1 + l * 256, bn2 + l * 256, nullptr, h, hbf, nullptr);
    }
  }

  pool_kernel<<<512, 256, 0, stream>>>(h, out);
}

// Round 14
// 579.398 us; speedup vs baseline: 1.0476x; 1.0476x over previous
//
#include <hip/hip_runtime.h>
#include <hip/hip_bf16.h>
#include <stdint.h>

// Problem constants (fixed by reference setup)
#define NATOMS 16384          // B*NPB = 512*32
#define ETOT   327680         // NATOMS*K (K=20 neighbors)
#define NLAYER 4

typedef __hip_bfloat16 bf16;
using bf16x8 = __attribute__((ext_vector_type(8))) short;   // MFMA A/B frag (4 VGPRs)
using bf16x4 = __attribute__((ext_vector_type(4))) short;   // 8B packed bf16
using f32x4  = __attribute__((ext_vector_type(4))) float;   // MFMA C/D frag

#define LDSF_STRIDE 260   // f32 words per barrier-bridge row

__device__ __forceinline__ float bf2f(short s) {
  union { float f; unsigned u; } x; x.u = ((unsigned)(unsigned short)s) << 16; return x.f;
}
__device__ __forceinline__ short f2bf(float f) {
  bf16 b = __float2bfloat16(f);
  return *(short*)&b;
}

__device__ __forceinline__ void async16(const void* g, void* l) {
  __builtin_amdgcn_global_load_lds(
      (const __attribute__((address_space(1))) unsigned int*)g,
      (__attribute__((address_space(3))) unsigned int*)l, 16, 0, 0);
}

// ---------------------------------------------------------------------------
// gemm_k: used once for the initial Prc = h0 @ Wrc (+be1 fold on cols<256).
// ---------------------------------------------------------------------------
template<int KTOT, int EPI, int MT>
__global__ void __launch_bounds__(256, 2)
gemm_k(const bf16* A, const bf16* A2, const bf16* B,
       bf16* Obf, int ldOut, const float* bias,
       float* Hf, bf16* Hbf)
{
  __shared__ __align__(16) char smem[49152];
  const int tid  = threadIdx.x;
  const int w    = tid >> 6;
  const int lane = tid & 63;
  const int q    = lane >> 4;
  const int t16  = lane & 15;
  const size_t row0 = (size_t)blockIdx.x * MT;
  const int ncol0 = blockIdx.y * 256;
  constexpr int MI = MT / 16;
  constexpr int AI = MT / 32;

  f32x4 acc[MI][4] = {};
  constexpr int NCHUNK = KTOT / 64;
  for (int kc = 0; kc < NCHUNK; ++kc) {
    const int k0 = kc * 64;
    __syncthreads();
    #pragma unroll
    for (int ii = 0; ii < AI; ++ii) {
      int i = w * AI + ii;
      int f = i * 64 + lane;
      int m = f >> 3, s = f & 7;
      int ko = s ^ (m & 7);
      async16(A + (row0 + (size_t)m) * KTOT + (size_t)(k0 + ko * 8), smem + i * 1024);
    }
    #pragma unroll
    for (int ii = 0; ii < 8; ++ii) {
      int i = w * 8 + ii;
      int f = i * 64 + lane;
      int n = f >> 3, s = f & 7;
      int ko = s ^ (n & 7);
      async16(B + (size_t)(ncol0 + n) * KTOT + (size_t)(k0 + ko * 8),
              smem + 16384 + i * 1024);
    }
    __syncthreads();
    #pragma unroll
    for (int ks = 0; ks < 2; ++ks) {
      bf16x8 av[MI]; bf16x8 bv[4];
      const int ko = q + 4 * ks;
      #pragma unroll
      for (int mi = 0; mi < MI; ++mi) {
        int m = 16 * mi + t16;
        int f = m * 8 + (ko ^ (m & 7));
        av[mi] = *(const bf16x8*)(smem + f * 16);
      }
      #pragma unroll
      for (int ni = 0; ni < 4; ++ni) {
        int n = 64 * w + 16 * ni + t16;
        int f = n * 8 + (ko ^ (n & 7));
        bv[ni] = *(const bf16x8*)(smem + 16384 + f * 16);
      }
      #pragma unroll
      for (int mi = 0; mi < MI; ++mi)
        #pragma unroll
        for (int ni = 0; ni < 4; ++ni)
          acc[mi][ni] = __builtin_amdgcn_mfma_f32_16x16x32_bf16(
              av[mi], bv[ni], acc[mi][ni], 0, 0, 0);
    }
  }

  float* lds_f = (float*)smem;
  #pragma unroll
  for (int mi = 0; mi < MI; ++mi) {
    __syncthreads();
    #pragma unroll
    for (int ni = 0; ni < 4; ++ni)
      #pragma unroll
      for (int r = 0; r < 4; ++r)
        lds_f[(4 * q + r) * LDSF_STRIDE + 64 * w + 16 * ni + t16] = acc[mi][ni][r];
    __syncthreads();
    #pragma unroll
    for (int j = 0; j < 2; ++j) {
      int task = tid + 256 * j;
      int rr = task >> 5, cg = task & 31;
      int c0 = cg * 8;
      size_t rg = row0 + 16 * mi + rr;
      f32x4 v0 = *(const f32x4*)(lds_f + rr * LDSF_STRIDE + c0);
      f32x4 v1 = *(const f32x4*)(lds_f + rr * LDSF_STRIDE + c0 + 4);
      float v[8] = {v0[0], v0[1], v0[2], v0[3], v1[0], v1[1], v1[2], v1[3]};
      bf16x8 o;
      #pragma unroll
      for (int k = 0; k < 8; ++k) {
        float vv = v[k];
        if (bias != nullptr && ncol0 == 0) vv += bias[c0 + k];
        o[k] = f2bf(vv);
      }
      *(bf16x8*)(Obf + rg * ldOut + (ncol0 + c0)) = o;
    }
  }
}

// ---------------------------------------------------------------------------
// Fused edge pipeline v5 (r11/r12-verified, unchanged).
// ---------------------------------------------------------------------------
#define WINC 40960
#define WINR 57856
#define SCOL 59968
#define SRAD 60288
#define WPITCH 528

__global__ void __launch_bounds__(256, 2)
edge_fused(const bf16* Wgp_l, const bf16* W2p_l, const float* off,
           const float* pos, const int* eidx, const bf16* Prc,
           const float* wrad, const float* be2, bf16* Agg)
{
  __shared__ __align__(16) char smem[60608];
  int*   s_col = (int*)  (smem + SCOL);
  float* s_rad = (float*)(smem + SRAD);

  const int tid  = threadIdx.x;
  const int w    = tid >> 6;
  const int lane = tid & 63;
  const int q    = lane >> 4;
  const int t16  = lane & 15;
  const int blk  = blockIdx.x;
  const int node0  = (blk >> 3) * 32;
  const int rnode0 = blk * 4;
  const int ebase  = blk * 80;

  bf16x8 wgf[4][2];
  #pragma unroll
  for (int fi = 0; fi < 4; ++fi)
    #pragma unroll
    for (int ks = 0; ks < 2; ++ks)
      wgf[fi][ks] = *(const bf16x8*)(Wgp_l + (size_t)(((fi * 2 + ks) * 4 + w) * 512)
                                     + lane * 8);

  {
    int row = tid >> 3, seg = tid & 7;
    const bf16* src = Prc + (size_t)(node0 + row) * 512 + 256 + seg * 32;
    char* dst = smem + WINC + row * WPITCH + seg * 64;
    #pragma unroll
    for (int j = 0; j < 4; ++j)
      *(bf16x8*)(dst + j * 16) = *(const bf16x8*)(src + j * 8);
  }
  if (tid < 128) {
    int row = tid >> 5, seg = tid & 31;
    *(bf16x8*)(smem + WINR + row * WPITCH + seg * 16) =
        *(const bf16x8*)(Prc + (size_t)(rnode0 + row) * 512 + seg * 8);
  }

  if (tid < 80) {
    int e = ebase + tid;
    int rg = rnode0 + tid / 20;            // row node = e/20 (setup identity)
    int cg = eidx[ETOT + e];
    float dx = pos[cg * 3 + 0] - pos[rg * 3 + 0];
    float dy = pos[cg * 3 + 1] - pos[rg * 3 + 1];
    float dz = pos[cg * 3 + 2] - pos[rg * 3 + 2];
    float d2 = dx * dx + dy * dy + dz * dz;
    s_col[tid] = cg & 31;
    s_rad[tid] = 0.01f * d2;
    float d = sqrtf(d2);
    const float GC = -0.5f / ((5.0f / 63.0f) * (5.0f / 63.0f));
    #pragma unroll
    for (int oct = 0; oct < 8; ++oct) {
      bf16x8 v;
      #pragma unroll
      for (int j = 0; j < 8; ++j) {
        float t = d - off[oct * 8 + j];
        v[j] = f2bf(__expf(GC * t * t));
      }
      int f = tid * 8 + (oct ^ (tid & 7));
      *(bf16x8*)(smem + f * 16) = v;
    }
  }
  __syncthreads();                         // (#1)

  f32x4 acc1[4][5] = {};
  #pragma unroll
  for (int ks = 0; ks < 2; ++ks) {
    const int ko = q + 4 * ks;
    bf16x8 gv[5];
    #pragma unroll
    for (int ci = 0; ci < 5; ++ci) {
      int e = 16 * ci + t16;
      int f = e * 8 + (ko ^ (e & 7));
      gv[ci] = *(const bf16x8*)(smem + f * 16);
    }
    #pragma unroll
    for (int fi = 0; fi < 4; ++fi)
      #pragma unroll
      for (int ci = 0; ci < 5; ++ci)
        acc1[fi][ci] = __builtin_amdgcn_mfma_f32_16x16x32_bf16(
            wgf[fi][ks], gv[ci], acc1[fi][ci], 0, 0, 0);
  }
  __syncthreads();                         // (#2)

  {
    f32x4 tw[4];
    #pragma unroll
    for (int fi = 0; fi < 4; ++fi)
      tw[fi] = *(const f32x4*)(wrad + 64 * w + 16 * fi + 4 * q);
    #pragma unroll
    for (int ci = 0; ci < 5; ++ci) {
      int e = 16 * ci + t16;
      int rl = e / 20;
      int cl = s_col[e];
      float rad = s_rad[e];
      #pragma unroll
      for (int fi = 0; fi < 4; ++fi) {
        int fb = 64 * w + 16 * fi + 4 * q;
        bf16x4 pr = *(const bf16x4*)(smem + WINR + rl * WPITCH + fb * 2);
        bf16x4 pc = *(const bf16x4*)(smem + WINC + cl * WPITCH + fb * 2);
        bf16x4 o;
        #pragma unroll
        for (int r = 0; r < 4; ++r) {
          float val = acc1[fi][ci][r] + rad * tw[fi][r]
                    + bf2f(pr[r]) + bf2f(pc[r]);
          o[r] = f2bf(fmaxf(val, 0.f));
        }
        int u = (16 * w + 4 * fi + q) ^ (e & 14);
        *(bf16x4*)(smem + e * 512 + u * 8) = o;
      }
    }
  }
  __syncthreads();                         // (#3)

  f32x4 acc2[5][4] = {};
  #pragma unroll
  for (int kc = 0; kc < 4; ++kc) {
    bf16x8 bv[4][2];
    #pragma unroll
    for (int ni = 0; ni < 4; ++ni)
      #pragma unroll
      for (int ks = 0; ks < 2; ++ks) {
        int frag = kc * 8 + ks * 4 + ni;
        bv[ni][ks] = *(const bf16x8*)(W2p_l + (size_t)((frag * 4 + w) * 512)
                                      + lane * 8);
      }
    #pragma unroll
    for (int ks = 0; ks < 2; ++ks) {
      const int ko = q + 4 * ks;
      bf16x8 av[5];
      #pragma unroll
      for (int mi = 0; mi < 5; ++mi) {
        int e = 16 * mi + t16;
        int ub = (2 * (8 * kc + ko)) ^ (t16 & 14);
        av[mi] = *(const bf16x8*)(smem + e * 512 + ub * 8);
      }
      #pragma unroll
      for (int mi = 0; mi < 5; ++mi)
        #pragma unroll
        for (int ni = 0; ni < 4; ++ni)
          acc2[mi][ni] = __builtin_amdgcn_mfma_f32_16x16x32_bf16(
              av[mi], bv[ni][ks], acc2[mi][ni], 0, 0, 0);
    }
  }

  #pragma unroll
  for (int ni = 0; ni < 4; ++ni) {
    float b = be2[64 * w + 16 * ni + t16];
    float pp[5];
    #pragma unroll
    for (int mi = 0; mi < 5; ++mi) {
      float s = 0.f;
      #pragma unroll
      for (int r = 0; r < 4; ++r) s += fmaxf(acc2[mi][ni][r] + b, 0.f);
      pp[mi] = s;
    }
    #pragma unroll
    for (int nn = 0; nn < 4; ++nn) {
      float s = 0.f;
      #pragma unroll
      for (int mi = 0; mi < 5; ++mi) {
        int g = 4 * mi + q;
        if (g >= 5 * nn && g <= 5 * nn + 4) s += pp[mi];
      }
      s += __shfl_xor(s, 16, 64);
      s += __shfl_xor(s, 32, 64);
      if (q == nn)
        Agg[(size_t)(rnode0 + nn) * 256 + 64 * w + 16 * ni + t16] =
            __float2bfloat16(s);
    }
  }
}

// ---------------------------------------------------------------------------
// node_fused v2 (r13 structure, SWIZZLE FIX in bridge2's T-write):
// T-tile convention everywhere: octet oct (16B, features 8oct..8oct+7) of
// row r lives at byte 16*(oct ^ ((r>>1)&7))... expressed as 8B units:
// unit u stored at u ^ (r&14). GEMM1-t-write uses u ^ (node&14) [ok],
// GEMM2/GEMM3 read ub = 2*oct ^ (r&14) [ok], bridge2 now writes 16B slot
// s = cg ^ ((rl>>1)&7)  [was (cg&24)|((cg&7)^(rl&7)) -- the r13 bug].
// ---------------------------------------------------------------------------
template<bool DO_PRC>
__global__ void __launch_bounds__(256, 2)
node_fused(const bf16* Hbf_in, const bf16* Agg, const bf16* Wn1p_l,
           const bf16* Wn2p_l, const bf16* Wrcp_n,
           const float* bn1, const float* bn2, const float* be1_n,
           float* Hf, bf16* Hbf, bf16* Prc)
{
  __shared__ __align__(16) char smem[49152];  // A-tile 32K (bridge reuse) | T 16K @32768
  __shared__ float s_bn1[256];
  __shared__ float s_bn2[256];
  char* T = smem + 32768;
  float* lds_f = (float*)smem;

  const int tid  = threadIdx.x;
  const int w    = tid >> 6;
  const int lane = tid & 63;
  const int q    = lane >> 4;
  const int t16  = lane & 15;
  const size_t row0 = (size_t)blockIdx.x * 32;

  // ---- stage [h|agg] tile (32 rows x 512 k), issue i stages row i ----
  #pragma unroll
  for (int ii = 0; ii < 8; ++ii) {
    int i = w * 8 + ii;                    // row
    int ko = (lane & 56) | ((lane & 7) ^ (i & 7));
    const bf16* srcp = ((lane < 32) ? Hbf_in : Agg)
                     + (row0 + (size_t)i) * 256 + ((ko * 8) & 255);
    async16(srcp, smem + i * 1024);
  }
  s_bn1[tid] = bn1[tid];
  s_bn2[tid] = bn2[tid];
  __syncthreads();                         // (#1) tile + biases ready

  // ---- GEMM1 transposed: D[feature][node], K=512 ----
  f32x4 acc1[4][2] = {};                   // [fi][ci]
  for (int kc = 0; kc < 8; ++kc) {
    #pragma unroll
    for (int ks = 0; ks < 2; ++ks) {
      const int ko = kc * 8 + q + 4 * ks;
      bf16x8 af[4];
      #pragma unroll
      for (int fi = 0; fi < 4; ++fi)       // Wn1p: coalesced global frags
        af[fi] = *(const bf16x8*)(Wn1p_l +
                   (size_t)((fi * 16 + kc * 2 + ks) * 4 + w) * 512 + lane * 8);
      bf16x8 bv[2];
      #pragma unroll
      for (int ci = 0; ci < 2; ++ci) {     // tile: node = 16ci + t16
        int node = 16 * ci + t16;
        int sl = (ko & 56) | ((ko & 7) ^ (node & 7));
        bv[ci] = *(const bf16x8*)(smem + node * 1024 + sl * 16);
      }
      #pragma unroll
      for (int fi = 0; fi < 4; ++fi)
        #pragma unroll
        for (int ci = 0; ci < 2; ++ci)
          acc1[fi][ci] = __builtin_amdgcn_mfma_f32_16x16x32_bf16(
              af[fi], bv[ci], acc1[fi][ci], 0, 0, 0);
    }
  }

  // ---- t = relu(acc1 + bn1) -> T directly (no bridge) ----
  #pragma unroll
  for (int ci = 0; ci < 2; ++ci) {
    int node = 16 * ci + t16;
    #pragma unroll
    for (int fi = 0; fi < 4; ++fi) {
      int fb = 64 * w + 16 * fi + 4 * q;
      f32x4 tb = *(const f32x4*)(s_bn1 + fb);
      bf16x4 o;
      #pragma unroll
      for (int r = 0; r < 4; ++r)
        o[r] = f2bf(fmaxf(acc1[fi][ci][r] + tb[r], 0.f));
      int u = (16 * w + 4 * fi + q) ^ (node & 14);
      *(bf16x4*)(T + node * 512 + u * 8) = o;
    }
  }
  __syncthreads();                         // (#2) T complete

  // ---- GEMM2: t @ Wn2 (K=256), A from T, B packed-global ----
  f32x4 acc2[2][4] = {};
  #pragma unroll
  for (int kc = 0; kc < 4; ++kc) {
    bf16x8 bv[4][2];
    #pragma unroll
    for (int ni = 0; ni < 4; ++ni)
      #pragma unroll
      for (int ks = 0; ks < 2; ++ks) {
        int frag = kc * 8 + ks * 4 + ni;
        bv[ni][ks] = *(const bf16x8*)(Wn2p_l + (size_t)((frag * 4 + w) * 512)
                                      + lane * 8);
      }
    #pragma unroll
    for (int ks = 0; ks < 2; ++ks) {
      const int ko = q + 4 * ks;
      bf16x8 av[2];
      #pragma unroll
      for (int mi = 0; mi < 2; ++mi) {
        int row = 16 * mi + t16;
        int ub = (2 * (8 * kc + ko)) ^ (t16 & 14);
        av[mi] = *(const bf16x8*)(T + row * 512 + ub * 8);
      }
      #pragma unroll
      for (int mi = 0; mi < 2; ++mi)
        #pragma unroll
        for (int ni = 0; ni < 4; ++ni)
          acc2[mi][ni] = __builtin_amdgcn_mfma_f32_16x16x32_bf16(
              av[mi], bv[ni][ks], acc2[mi][ni], 0, 0, 0);
    }
  }

  // ---- bridge2: h' = 2h + acc2 + bn2 -> Hf, Hbf, T ----
  #pragma unroll
  for (int mi = 0; mi < 2; ++mi) {
    __syncthreads();
    #pragma unroll
    for (int ni = 0; ni < 4; ++ni)
      #pragma unroll
      for (int r = 0; r < 4; ++r)
        lds_f[(4 * q + r) * LDSF_STRIDE + 64 * w + 16 * ni + t16] = acc2[mi][ni][r];
    __syncthreads();
    #pragma unroll
    for (int j = 0; j < 2; ++j) {
      int task = tid + 256 * j;
      int rr = task >> 5, cg = task & 31;
      int c0 = cg * 8;
      int rl = 16 * mi + rr;
      size_t rg = row0 + rl;
      f32x4 v0 = *(const f32x4*)(lds_f + rr * LDSF_STRIDE + c0);
      f32x4 v1 = *(const f32x4*)(lds_f + rr * LDSF_STRIDE + c0 + 4);
      float v[8] = {v0[0], v0[1], v0[2], v0[3], v1[0], v1[1], v1[2], v1[3]};
      f32x4 h0 = *(const f32x4*)(Hf + rg * 256 + c0);
      f32x4 h1 = *(const f32x4*)(Hf + rg * 256 + c0 + 4);
      float hh[8] = {h0[0], h0[1], h0[2], h0[3], h1[0], h1[1], h1[2], h1[3]};
      bf16x8 o; f32x4 n0, n1;
      #pragma unroll
      for (int k = 0; k < 8; ++k) {
        float hn = 2.f * hh[k] + v[k] + s_bn2[c0 + k];
        o[k] = f2bf(hn);
        if (k < 4) n0[k] = hn; else n1[k - 4] = hn;
      }
      *(f32x4*)(Hf + rg * 256 + c0)     = n0;
      *(f32x4*)(Hf + rg * 256 + c0 + 4) = n1;
      *(bf16x8*)(Hbf + rg * 256 + c0) = o;
      int s = cg ^ ((rl >> 1) & 7);        // FIX: match GEMM3 read swizzle
      *(bf16x8*)(T + rl * 512 + s * 16) = o;
    }
  }

  // ---- GEMM3 + epilogue: Prc_next = h' @ Wrc (+be1 on nh==0) ----
  if constexpr (DO_PRC) {
    __syncthreads();                       // T(h') complete
    #pragma unroll
    for (int nh = 0; nh < 2; ++nh) {
      f32x4 acc3[2][4] = {};
      #pragma unroll
      for (int kc = 0; kc < 4; ++kc) {
        bf16x8 bv[4][2];
        #pragma unroll
        for (int ni = 0; ni < 4; ++ni)
          #pragma unroll
          for (int ks = 0; ks < 2; ++ks) {
            int frag = kc * 8 + ks * 4 + ni;
            bv[ni][ks] = *(const bf16x8*)(Wrcp_n + (size_t)nh * 65536 +
                                          (size_t)((frag * 4 + w) * 512) + lane * 8);
          }
        #pragma unroll
        for (int ks = 0; ks < 2; ++ks) {
          const int ko = q + 4 * ks;
          bf16x8 av[2];
          #pragma unroll
          for (int mi = 0; mi < 2; ++mi) {
            int row = 16 * mi + t16;
            int ub = (2 * (8 * kc + ko)) ^ (t16 & 14);
            av[mi] = *(const bf16x8*)(T + row * 512 + ub * 8);
          }
          #pragma unroll
          for (int mi = 0; mi < 2; ++mi)
            #pragma unroll
            for (int ni = 0; ni < 4; ++ni)
              acc3[mi][ni] = __builtin_amdgcn_mfma_f32_16x16x32_bf16(
                  av[mi], bv[ni][ks], acc3[mi][ni], 0, 0, 0);
        }
      }
      #pragma unroll
      for (int mi = 0; mi < 2; ++mi) {
        __syncthreads();
        #pragma unroll
        for (int ni = 0; ni < 4; ++ni)
          #pragma unroll
          for (int r = 0; r < 4; ++r)
            lds_f[(4 * q + r) * LDSF_STRIDE + 64 * w + 16 * ni + t16] = acc3[mi][ni][r];
        __syncthreads();
        #pragma unroll
        for (int j = 0; j < 2; ++j) {
          int task = tid + 256 * j;
          int rr = task >> 5, cg = task & 31;
          int c0 = cg * 8;
          size_t rg = row0 + 16 * mi + rr;
          f32x4 v0 = *(const f32x4*)(lds_f + rr * LDSF_STRIDE + c0);
          f32x4 v1 = *(const f32x4*)(lds_f + rr * LDSF_STRIDE + c0 + 4);
          float v[8] = {v0[0], v0[1], v0[2], v0[3], v1[0], v1[1], v1[2], v1[3]};
          bf16x8 o;
          #pragma unroll
          for (int k = 0; k < 8; ++k) {
            float vv = v[k];
            if (nh == 0) vv += be1_n[c0 + k];
            o[k] = f2bf(vv);
          }
          *(bf16x8*)(Prc + rg * 512 + nh * 256 + c0) = o;
        }
      }
    }
  }
}

// ---------------------------------------------------------------------------
// Prep kernels
// ---------------------------------------------------------------------------
__global__ void wrct_kernel(const float* We1, bf16* WrcT) {
  int idx = blockIdx.x * 256 + threadIdx.x;         // 512*256 (layer 0 only)
  int k = idx & 255, np = (idx >> 8) & 511;
  float v = (np < 256)
      ? We1[((size_t)k) * 256 + np]
      : We1[((size_t)256 + k) * 256 + (np - 256)];
  WrcT[idx] = __float2bfloat16(v);
}
// packed Wg fragments: [l][fi*2+ks][w][lane][j]
__global__ void wgp_kernel(const float* We1, bf16* Wgp) {
  int idx = blockIdx.x * 256 + threadIdx.x;         // L*16384
  int i = idx & 16383, l = idx >> 14;
  int j = i & 7, lane = (i >> 3) & 63, w = (i >> 9) & 3, fr = i >> 11;
  int fi = fr >> 1, ks = fr & 1;
  int t16 = lane & 15, q = lane >> 4;
  int g = (q + 4 * ks) * 8 + j;
  int feat = 64 * w + 16 * fi + t16;
  Wgp[idx] = __float2bfloat16(We1[((size_t)l * 577 + 513 + g) * 256 + feat]);
}
// generic 256x256 weight -> packed fragments [l][kc*8+ks*4+ni][w][lane][j]
__global__ void w2p_kernel(const float* W, bf16* Wp) {
  int idx = blockIdx.x * 256 + threadIdx.x;         // L*65536
  int i = idx & 65535, l = idx >> 16;
  int j = i & 7, lane = (i >> 3) & 63, w = (i >> 9) & 3, fr = i >> 11;
  int ni = fr & 3, ks = (fr >> 2) & 1, kc = fr >> 3;
  int t16 = lane & 15, q = lane >> 4;
  int k = kc * 64 + (q + 4 * ks) * 8 + j;
  int n = 64 * w + 16 * ni + t16;
  Wp[idx] = __float2bfloat16(W[((size_t)l * 256 + k) * 256 + n]);
}
// Wrc packed fragments: [l][nh][kc*8+ks*4+ni][w][lane][j]
__global__ void wrcp_kernel(const float* We1, bf16* Wrcp) {
  int idx = blockIdx.x * 256 + threadIdx.x;         // L*2*65536
  int i = idx & 65535, nh = (idx >> 16) & 1, l = idx >> 17;
  int j = i & 7, lane = (i >> 3) & 63, w = (i >> 9) & 3, fr = i >> 11;
  int ni = fr & 3, ks = (fr >> 2) & 1, kc = fr >> 3;
  int t16 = lane & 15, q = lane >> 4;
  int k = kc * 64 + (q + 4 * ks) * 8 + j;
  int n = 64 * w + 16 * ni + t16;
  Wrcp[idx] = __float2bfloat16(We1[((size_t)l * 577 + nh * 256 + k) * 256 + n]);
}
// Wn1 feature-major packed fragments: [l][fi*16+kc*2+ks][w][lane][j], K=512
__global__ void wn1p_kernel(const float* Wn1, bf16* Wn1p) {
  int idx = blockIdx.x * 256 + threadIdx.x;         // L*131072
  int i = idx & 131071, l = idx >> 17;
  int j = i & 7, lane = (i >> 3) & 63, w = (i >> 9) & 3, fr = i >> 11;
  int fi = fr >> 4, kc = (fr & 15) >> 1, ks = fr & 1;
  int t16 = lane & 15, q = lane >> 4;
  int feat = 64 * w + 16 * fi + t16;
  int k = kc * 64 + (q + 4 * ks) * 8 + j;
  Wn1p[idx] = __float2bfloat16(Wn1[((size_t)l * 512 + k) * 256 + feat]);
}
__global__ void wrad_kernel(const float* We1, float* wrad) {
  int idx = blockIdx.x * 256 + threadIdx.x;         // L*256
  int n = idx & 255, l = idx >> 8;
  wrad[idx] = We1[((size_t)l * 577 + 512) * 256 + n];
}

__global__ void h0_kernel(const int* types, const float* emb, float* h, bf16* hbf) {
  int i = blockIdx.x, c = threadIdx.x;
  float v = emb[(size_t)(types[i] - 1) * 256 + c];
  h[(size_t)i * 256 + c] = v;
  hbf[(size_t)i * 256 + c] = __float2bfloat16(v);
}

__global__ void pool_kernel(const float* h, float* out) {
  int b = blockIdx.x, c = threadIdx.x;
  float s = 0.f;
  #pragma unroll
  for (int j = 0; j < 32; ++j) s += h[((size_t)b * 32 + j) * 256 + c];
  out[(size_t)b * 256 + c] = s * (1.0f / 32.0f);
}

// ---------------------------------------------------------------------------
extern "C" void kernel_launch(void* const* d_in, const int* in_sizes, int n_in,
                              void* d_out, int out_size, void* d_ws, size_t ws_size,
                              hipStream_t stream) {
  const float* pos   = (const float*)d_in[0];
  const int*   atype = (const int*)  d_in[1];
  const int*   eidx  = (const int*)  d_in[2];
  const float* emb   = (const float*)d_in[4];
  const float* off   = (const float*)d_in[5];
  const float* We1   = (const float*)d_in[6];
  const float* be1   = (const float*)d_in[7];
  const float* We2   = (const float*)d_in[8];
  const float* be2   = (const float*)d_in[9];
  const float* Wn1   = (const float*)d_in[10];
  const float* bn1   = (const float*)d_in[11];
  const float* Wn2   = (const float*)d_in[12];
  const float* bn2   = (const float*)d_in[13];
  float* out = (float*)d_out;

  size_t o = 0;
  auto carve = [&](size_t bytes) {
    void* p = (char*)d_ws + o;
    o += (bytes + 255) & ~(size_t)255;
    return p;
  };
  float* h     = (float*)carve((size_t)NATOMS * 256 * 4);   // 16 MB
  bf16*  hbf   = (bf16*) carve((size_t)NATOMS * 256 * 2);   //  8 MB
  bf16*  Prc   = (bf16*) carve((size_t)NATOMS * 512 * 2);   // 16 MB
  bf16*  aggbf = (bf16*) carve((size_t)NATOMS * 256 * 2);   //  8 MB
  bf16*  WrcT  = (bf16*) carve((size_t)512 * 256 * 2);      // layer-0 only
  bf16*  Wgp   = (bf16*) carve((size_t)NLAYER * 16384 * 2);
  bf16*  W2p   = (bf16*) carve((size_t)NLAYER * 65536 * 2);
  bf16*  Wn1p  = (bf16*) carve((size_t)NLAYER * 131072 * 2);
  bf16*  Wn2p  = (bf16*) carve((size_t)NLAYER * 65536 * 2);
  bf16*  Wrcp  = (bf16*) carve((size_t)NLAYER * 2 * 65536 * 2);
  float* wradp = (float*)carve((size_t)NLAYER * 256 * 4);

  // ---- prep ----
  wrct_kernel<<< 512, 256, 0, stream>>>(We1, WrcT);
  wgp_kernel <<< 256, 256, 0, stream>>>(We1, Wgp);
  w2p_kernel <<<1024, 256, 0, stream>>>(We2, W2p);
  w2p_kernel <<<1024, 256, 0, stream>>>(Wn2, Wn2p);
  wrcp_kernel<<<2048, 256, 0, stream>>>(We1, Wrcp);
  wn1p_kernel<<<2048, 256, 0, stream>>>(Wn1, Wn1p);
  wrad_kernel<<<   4, 256, 0, stream>>>(We1, wradp);
  h0_kernel  <<<NATOMS, 256, 0, stream>>>(atype, emb, h, hbf);

  // initial Prc for layer 0 (be1 folded into cols 0..255)
  gemm_k<256, 0, 64><<<dim3(256, 2), 256, 0, stream>>>(
      hbf, nullptr, WrcT, Prc, 512, be1, nullptr, nullptr);

  for (int l = 0; l < NLAYER; ++l) {
    edge_fused<<<ETOT / 80, 256, 0, stream>>>(
        Wgp + (size_t)l * 16384, W2p + (size_t)l * 65536, off, pos,
        eidx, Prc, wradp + l * 256, be2 + l * 256, aggbf);
    if (l < NLAYER - 1) {
      node_fused<true><<<512, 256, 0, stream>>>(
          hbf, aggbf, Wn1p + (size_t)l * 131072, Wn2p + (size_t)l * 65536,
          Wrcp + (size_t)(l + 1) * 131072, bn1 + l * 256, bn2 + l * 256,
          be1 + (l + 1) * 256, h, hbf, Prc);
    } else {
      node_fused<false><<<512, 256, 0, stream>>>(
          hbf, aggbf, Wn1p + (size_t)l * 131072, Wn2p + (size_t)l * 65536,
          nullptr, bn1 + l * 256, bn2 + l * 256, nullptr, h, hbf, nullptr);
    }
  }

  pool_kernel<<<512, 256, 0, stream>>>(h, out);
}